// Round 3
// baseline (20520.724 us; speedup 1.0000x reference)
//
#include <hip/hip_runtime.h>
#include <hip/hip_fp16.h>

#define N_VAR 256
#define M_CON 512
#define BATCH 64
#define SIGMA_C 1e-6f
#define RHO_C 0.1f
#define ALPHA_C 1.6f
#define NITERS 500

// ---------------------------------------------------------------------------
// K1: transpose A [512][256] -> At [256][512] per batch
// ---------------------------------------------------------------------------
__global__ __launch_bounds__(256) void k_transpose(const float* __restrict__ A,
                                                   float* __restrict__ At) {
  __shared__ float tile[32][33];
  int b = blockIdx.z;
  int n0 = blockIdx.x * 32;
  int m0 = blockIdx.y * 32;
  const float* Ab = A + (size_t)b * (M_CON * N_VAR);
  float* Atb = At + (size_t)b * (M_CON * N_VAR);
  int tx = threadIdx.x, ty = threadIdx.y;  // (32, 8)
#pragma unroll
  for (int j = 0; j < 32; j += 8)
    tile[ty + j][tx] = Ab[(size_t)(m0 + ty + j) * N_VAR + n0 + tx];
  __syncthreads();
#pragma unroll
  for (int j = 0; j < 32; j += 8)
    Atb[(size_t)(n0 + ty + j) * M_CON + m0 + tx] = tile[tx][ty + j];
}

// ---------------------------------------------------------------------------
// K2: batched NT GEMM  C[i][j] = alpha * sum_k X[i][k]*Y[j][k]  (+ diag)
// ---------------------------------------------------------------------------
__global__ __launch_bounds__(256) void k_ntgemm(
    const float* __restrict__ X, const float* __restrict__ Y,
    float* __restrict__ C, int I, int J, int K,
    long long bsX, long long bsY, long long bsC, float alpha,
    const float* __restrict__ diagv, int tilesJ) {
  int b = blockIdx.y;
  int ti = blockIdx.x / tilesJ, tj = blockIdx.x % tilesJ;
  int i0 = ti * 128, j0 = tj * 128;
  const float* Xb = X + (size_t)b * bsX;
  const float* Yb = Y + (size_t)b * bsY;
  float* Cb = C + (size_t)b * bsC;
  __shared__ float Xs[16][128];
  __shared__ float Ys[16][128];
  int tid = threadIdx.x;
  int tx = tid & 15, ty = tid >> 4;
  float acc[8][8];
#pragma unroll
  for (int r = 0; r < 8; ++r)
#pragma unroll
    for (int c = 0; c < 8; ++c) acc[r][c] = 0.0f;

  for (int kk = 0; kk < K; kk += 16) {
#pragma unroll
    for (int v = 0; v < 2; ++v) {
      int idx = v * 256 + tid;
      int row = idx >> 2;
      int k4 = (idx & 3) * 4;
      float4 gx = *(const float4*)(Xb + (size_t)(i0 + row) * K + kk + k4);
      Xs[k4 + 0][row] = gx.x; Xs[k4 + 1][row] = gx.y;
      Xs[k4 + 2][row] = gx.z; Xs[k4 + 3][row] = gx.w;
      float4 gy = *(const float4*)(Yb + (size_t)(j0 + row) * K + kk + k4);
      Ys[k4 + 0][row] = gy.x; Ys[k4 + 1][row] = gy.y;
      Ys[k4 + 2][row] = gy.z; Ys[k4 + 3][row] = gy.w;
    }
    __syncthreads();
#pragma unroll
    for (int k = 0; k < 16; ++k) {
      float xr[8], yr[8];
      *(float4*)&xr[0] = *(float4*)&Xs[k][ty * 8];
      *(float4*)&xr[4] = *(float4*)&Xs[k][ty * 8 + 4];
      *(float4*)&yr[0] = *(float4*)&Ys[k][tx * 8];
      *(float4*)&yr[4] = *(float4*)&Ys[k][tx * 8 + 4];
#pragma unroll
      for (int r = 0; r < 8; ++r)
#pragma unroll
        for (int c = 0; c < 8; ++c) acc[r][c] += xr[r] * yr[c];
    }
    __syncthreads();
  }
#pragma unroll
  for (int r = 0; r < 8; ++r) {
    int gi = i0 + ty * 8 + r;
#pragma unroll
    for (int c = 0; c < 8; ++c) {
      int gj = j0 + tx * 8 + c;
      float val = acc[r][c] * alpha;
      if (diagv != nullptr && gi == gj) val += diagv[(size_t)b * N_VAR + gi] + SIGMA_C;
      Cb[(size_t)gi * J + gj] = val;
    }
  }
}

// ---------------------------------------------------------------------------
// K3: in-place Gauss-Jordan inversion (SPD, diag-dominant; no pivoting).
// ---------------------------------------------------------------------------
__global__ __launch_bounds__(1024) void k_invert(const float* __restrict__ Mk,
                                                 float* __restrict__ Mi) {
  int b = blockIdx.x;
  const float* src = Mk + (size_t)b * 65536;
  float* dst = Mi + (size_t)b * 65536;
  int t = threadIdx.x;
  int c = t & 255, rq = t >> 8;
  float a[64];
#pragma unroll
  for (int j = 0; j < 64; ++j) a[j] = src[j * 1024 + t];

  __shared__ float colP[2][256];
  __shared__ float rowB[2][256];

  for (int k = 0; k < 256; ++k) {
    int cur = k & 1;
    int kj = k >> 2, kq = k & 3;
    if (c == k) {
      float4* cp4 = (float4*)&colP[cur][64 * rq];
#pragma unroll
      for (int jj = 0; jj < 16; ++jj)
        cp4[jj] = make_float4(a[4 * jj], a[4 * jj + 1], a[4 * jj + 2], a[4 * jj + 3]);
    }
    __syncthreads();
    float pivinv = 1.0f / colP[cur][kj + 64 * kq];
    if (rq == kq) {
      float v = (c == k) ? pivinv : a[kj] * pivinv;
      a[kj] = v;
      rowB[cur][c] = v;
    }
    __syncthreads();
    float rb = rowB[cur][c];
    float keep = a[kj];
    const float4* cp4 = (const float4*)&colP[cur][64 * rq];
#pragma unroll
    for (int jj = 0; jj < 16; ++jj) {
      float4 cv = cp4[jj];
      a[4 * jj + 0] -= rb * cv.x;
      a[4 * jj + 1] -= rb * cv.y;
      a[4 * jj + 2] -= rb * cv.z;
      a[4 * jj + 3] -= rb * cv.w;
    }
    if (rq == kq) a[kj] = keep;
    if (c == k) {
#pragma unroll
      for (int jj = 0; jj < 16; ++jj) {
        float4 cv = cp4[jj];
        a[4 * jj + 0] = -pivinv * cv.x;
        a[4 * jj + 1] = -pivinv * cv.y;
        a[4 * jj + 2] = -pivinv * cv.z;
        a[4 * jj + 3] = -pivinv * cv.w;
      }
      if (rq == kq) a[kj] = pivinv;
    }
  }
#pragma unroll
  for (int j = 0; j < 64; ++j) dst[j * 1024 + t] = a[j];
}

// ---------------------------------------------------------------------------
// K4a: h = Minv * q  (column access via symmetry)
// ---------------------------------------------------------------------------
__global__ __launch_bounds__(256) void k_matvec_h(const float* __restrict__ Mi,
                                                  const float* __restrict__ q,
                                                  float* __restrict__ h) {
  int b = blockIdx.x, t = threadIdx.x;
  __shared__ float qs[256];
  qs[t] = q[(size_t)b * 256 + t];
  __syncthreads();
  const float* Mb = Mi + (size_t)b * 65536;
  float acc = 0.0f;
  for (int k = 0; k < 256; ++k) acc += Mb[(size_t)k * 256 + t] * qs[k];
  h[(size_t)b * 256 + t] = acc;
}

// K4b: d = A * h  via At columns
__global__ __launch_bounds__(512) void k_matvec_d(const float* __restrict__ At,
                                                  const float* __restrict__ h,
                                                  float* __restrict__ d) {
  int b = blockIdx.x, t = threadIdx.x;
  __shared__ float hs[256];
  if (t < 256) hs[t] = h[(size_t)b * 256 + t];
  __syncthreads();
  const float* Ab = At + (size_t)b * 131072;
  float acc = 0.0f;
  for (int n = 0; n < 256; ++n) acc += Ab[(size_t)n * 512 + t] * hs[n];
  d[(size_t)b * 512 + t] = acc;
}

// ---------------------------------------------------------------------------
// K5: ADMM loop, fully register-resident G, ZERO cross-WG sync.
// 64 WGs x 1024 threads (1 WG/CU). Thread t: lane l=t&63, wave wv=t>>6,
// row-half rh=wv&1, col-chunk ck=wv>>1. Owns G rows rh*256+4l..+3, cols
// [ck*64, ck*64+64) -> 256 fp32 in VGPR/AGPR (unified file, ~290/wave < 512).
// Per iter: w (512 floats, LDS) read via wave-uniform ds_read_b128 =
// broadcast (conflict-free); 256 fmac/thread; partials in part[8][512];
// update phase (t<512) keeps z,y,S,l,u,d in registers. 2 barriers/iter.
// ---------------------------------------------------------------------------
__global__ __launch_bounds__(1024) void k_admm_r(
    const float* __restrict__ G, const float* __restrict__ dvec,
    const float* __restrict__ lv, const float* __restrict__ uv,
    float* __restrict__ Sbuf) {
  int b = blockIdx.x;
  int t = threadIdx.x;
  int l = t & 63, wv = t >> 6;
  int rh = wv & 1, ck = wv >> 1;   // row-half (0..1), col-chunk (0..7)
  int m0 = rh * 256 + 4 * l;       // 4 rows m0..m0+3
  int c0 = ck * 64;                // 64-column chunk (wave-uniform)

  __shared__ __align__(16) float ws[512];
  __shared__ __align__(16) float part[8][512];

  // --- load G strip into registers (one-time) ---
  const float* Gb = G + (size_t)b * 262144;
  float Greg[4][64];
#pragma unroll
  for (int r = 0; r < 4; ++r) {
    const float* gr = Gb + (size_t)(m0 + r) * 512 + c0;
#pragma unroll
    for (int jb = 0; jb < 16; ++jb) {
      float4 gv = *(const float4*)(gr + 4 * jb);
      Greg[r][4 * jb + 0] = gv.x; Greg[r][4 * jb + 1] = gv.y;
      Greg[r][4 * jb + 2] = gv.z; Greg[r][4 * jb + 3] = gv.w;
    }
  }

  // --- per-thread state for the update phase (threads 0..511) ---
  float zreg = 0.0f, yreg = 0.0f, Sreg = 0.0f;
  float lreg = 0.0f, ureg = 0.0f, dreg = 0.0f;
  if (t < 512) {
    lreg = lv[(size_t)b * 512 + t];
    ureg = uv[(size_t)b * 512 + t];
    dreg = dvec[(size_t)b * 512 + t];
    ws[t] = 0.0f;                   // w_0 = 0
  }

  const float4* wq4 = (const float4*)(ws + c0);  // wave-uniform base

  for (int it = 0; it < NITERS; ++it) {
    __syncthreads();                // B1: w_k visible to all

    // z~ partial: rows m0..m0+3, cols c0..c0+63
    float a0 = 0.0f, a1 = 0.0f, a2 = 0.0f, a3 = 0.0f;
#pragma unroll
    for (int jb = 0; jb < 16; ++jb) {
      float4 wq = wq4[jb];          // broadcast ds_read_b128 (uniform addr)
      a0 += Greg[0][4 * jb + 0] * wq.x + Greg[0][4 * jb + 1] * wq.y +
            Greg[0][4 * jb + 2] * wq.z + Greg[0][4 * jb + 3] * wq.w;
      a1 += Greg[1][4 * jb + 0] * wq.x + Greg[1][4 * jb + 1] * wq.y +
            Greg[1][4 * jb + 2] * wq.z + Greg[1][4 * jb + 3] * wq.w;
      a2 += Greg[2][4 * jb + 0] * wq.x + Greg[2][4 * jb + 1] * wq.y +
            Greg[2][4 * jb + 2] * wq.z + Greg[2][4 * jb + 3] * wq.w;
      a3 += Greg[3][4 * jb + 0] * wq.x + Greg[3][4 * jb + 1] * wq.y +
            Greg[3][4 * jb + 2] * wq.z + Greg[3][4 * jb + 3] * wq.w;
    }
    *(float4*)&part[ck][m0] = make_float4(a0, a1, a2, a3);
    __syncthreads();                // B2: partials visible

    if (t < 512) {
      float wold = ws[t];           // w_k
      Sreg = wold - 0.6f * Sreg;    // S <- w_k + (1-alpha)*S
      float p = part[0][t] + part[1][t] + part[2][t] + part[3][t] +
                part[4][t] + part[5][t] + part[6][t] + part[7][t];
      float zt = p - dreg;
      float zh = ALPHA_C * zt + (1.0f - ALPHA_C) * zreg;
      float zc = zh + yreg * (1.0f / RHO_C);
      zc = fminf(fmaxf(zc, lreg), ureg);
      yreg += RHO_C * (zh - zc);
      zreg = zc;
      ws[t] = RHO_C * zc - yreg;    // w_{k+1}
    }
  }

  if (t < 512) Sbuf[(size_t)b * 512 + t] = Sreg;
}

// ---------------------------------------------------------------------------
// K7: epilogue  x = Minv * (alpha * A^T S - q)
// ---------------------------------------------------------------------------
__global__ __launch_bounds__(256) void k_final(
    const float* __restrict__ A, const float* __restrict__ q,
    const float* __restrict__ Mi, const float* __restrict__ Sbuf,
    float* __restrict__ xout) {
  int b = blockIdx.x, t = threadIdx.x;  // t = n index
  __shared__ float Ssh[512];
  __shared__ float uu[256];
  for (int i = t; i < 512; i += 256) Ssh[i] = Sbuf[(size_t)b * 512 + i];
  __syncthreads();
  const float* Ab = A + (size_t)b * 131072;
  float acc = 0.0f;
  for (int m = 0; m < 512; ++m) acc += Ab[(size_t)m * 256 + t] * Ssh[m];
  uu[t] = ALPHA_C * acc - q[(size_t)b * 256 + t];
  __syncthreads();
  const float* Mb = Mi + (size_t)b * 65536;
  float x = 0.0f;
  for (int kk = 0; kk < 256; ++kk) x += Mb[(size_t)kk * 256 + t] * uu[kk];
  xout[(size_t)b * 256 + t] = x;
}

// ---------------------------------------------------------------------------
extern "C" void kernel_launch(void* const* d_in, const int* in_sizes, int n_in,
                              void* d_out, int out_size, void* d_ws, size_t ws_size,
                              hipStream_t stream) {
  (void)in_sizes; (void)n_in; (void)out_size; (void)ws_size;
  const float* P = (const float*)d_in[0];
  const float* q = (const float*)d_in[1];
  const float* Av = (const float*)d_in[2];
  const float* lv = (const float*)d_in[3];
  const float* uv = (const float*)d_in[4];
  float* xout = (float*)d_out;

  float* ws = (float*)d_ws;
  float* At = ws;                       // 64*256*512 floats; dies after k_matvec_d
  float* F  = ws;                       // alias of At
  float* Mi = ws + 8388608;             // 64*256*256
  float* Mk = ws + 12582912;            // dies after k_invert
  float* G  = ws + 12582912;            // 64*512*512 (over dead Mk)
  float* hv = ws + 29360128;            // 64*256
  float* dv = ws + 29376512;            // 64*512
  float* Sbuf = ws + 29409280;          // 64*512

  k_transpose<<<dim3(8, 16, 64), dim3(32, 8), 0, stream>>>(Av, At);
  k_ntgemm<<<dim3(4, 64), 256, 0, stream>>>(At, At, Mk, 256, 256, 512,
                                            131072LL, 131072LL, 65536LL,
                                            RHO_C, P, 2);
  k_invert<<<64, 1024, 0, stream>>>(Mk, Mi);
  k_matvec_h<<<64, 256, 0, stream>>>(Mi, q, hv);
  k_matvec_d<<<64, 512, 0, stream>>>(At, hv, dv);
  k_ntgemm<<<dim3(8, 64), 256, 0, stream>>>(Av, Mi, F, 512, 256, 256,
                                            131072LL, 65536LL, 131072LL,
                                            1.0f, nullptr, 2);
  k_ntgemm<<<dim3(16, 64), 256, 0, stream>>>(F, Av, G, 512, 512, 256,
                                             131072LL, 131072LL, 262144LL,
                                             1.0f, nullptr, 4);
  k_admm_r<<<64, 1024, 0, stream>>>(G, dv, lv, uv, Sbuf);
  k_final<<<64, 256, 0, stream>>>(Av, q, Mi, Sbuf, xout);
}

// Round 4
// 6827.468 us; speedup vs baseline: 3.0056x; 3.0056x over previous
//
#include <hip/hip_runtime.h>
#include <hip/hip_fp16.h>

#define N_VAR 256
#define M_CON 512
#define BATCH 64
#define SIGMA_C 1e-6f
#define RHO_C 0.1f
#define ALPHA_C 1.6f
#define NITERS 500

// ---------------------------------------------------------------------------
// K1: transpose A [512][256] -> At [256][512] per batch
// ---------------------------------------------------------------------------
__global__ __launch_bounds__(256) void k_transpose(const float* __restrict__ A,
                                                   float* __restrict__ At) {
  __shared__ float tile[32][33];
  int b = blockIdx.z;
  int n0 = blockIdx.x * 32;
  int m0 = blockIdx.y * 32;
  const float* Ab = A + (size_t)b * (M_CON * N_VAR);
  float* Atb = At + (size_t)b * (M_CON * N_VAR);
  int tx = threadIdx.x, ty = threadIdx.y;  // (32, 8)
#pragma unroll
  for (int j = 0; j < 32; j += 8)
    tile[ty + j][tx] = Ab[(size_t)(m0 + ty + j) * N_VAR + n0 + tx];
  __syncthreads();
#pragma unroll
  for (int j = 0; j < 32; j += 8)
    Atb[(size_t)(n0 + ty + j) * M_CON + m0 + tx] = tile[tx][ty + j];
}

// ---------------------------------------------------------------------------
// K2: batched NT GEMM  C[i][j] = alpha * sum_k X[i][k]*Y[j][k]  (+ diag)
// ---------------------------------------------------------------------------
__global__ __launch_bounds__(256) void k_ntgemm(
    const float* __restrict__ X, const float* __restrict__ Y,
    float* __restrict__ C, int I, int J, int K,
    long long bsX, long long bsY, long long bsC, float alpha,
    const float* __restrict__ diagv, int tilesJ) {
  int b = blockIdx.y;
  int ti = blockIdx.x / tilesJ, tj = blockIdx.x % tilesJ;
  int i0 = ti * 128, j0 = tj * 128;
  const float* Xb = X + (size_t)b * bsX;
  const float* Yb = Y + (size_t)b * bsY;
  float* Cb = C + (size_t)b * bsC;
  __shared__ float Xs[16][128];
  __shared__ float Ys[16][128];
  int tid = threadIdx.x;
  int tx = tid & 15, ty = tid >> 4;
  float acc[8][8];
#pragma unroll
  for (int r = 0; r < 8; ++r)
#pragma unroll
    for (int c = 0; c < 8; ++c) acc[r][c] = 0.0f;

  for (int kk = 0; kk < K; kk += 16) {
#pragma unroll
    for (int v = 0; v < 2; ++v) {
      int idx = v * 256 + tid;
      int row = idx >> 2;
      int k4 = (idx & 3) * 4;
      float4 gx = *(const float4*)(Xb + (size_t)(i0 + row) * K + kk + k4);
      Xs[k4 + 0][row] = gx.x; Xs[k4 + 1][row] = gx.y;
      Xs[k4 + 2][row] = gx.z; Xs[k4 + 3][row] = gx.w;
      float4 gy = *(const float4*)(Yb + (size_t)(j0 + row) * K + kk + k4);
      Ys[k4 + 0][row] = gy.x; Ys[k4 + 1][row] = gy.y;
      Ys[k4 + 2][row] = gy.z; Ys[k4 + 3][row] = gy.w;
    }
    __syncthreads();
#pragma unroll
    for (int k = 0; k < 16; ++k) {
      float xr[8], yr[8];
      *(float4*)&xr[0] = *(float4*)&Xs[k][ty * 8];
      *(float4*)&xr[4] = *(float4*)&Xs[k][ty * 8 + 4];
      *(float4*)&yr[0] = *(float4*)&Ys[k][tx * 8];
      *(float4*)&yr[4] = *(float4*)&Ys[k][tx * 8 + 4];
#pragma unroll
      for (int r = 0; r < 8; ++r)
#pragma unroll
        for (int c = 0; c < 8; ++c) acc[r][c] += xr[r] * yr[c];
    }
    __syncthreads();
  }
#pragma unroll
  for (int r = 0; r < 8; ++r) {
    int gi = i0 + ty * 8 + r;
#pragma unroll
    for (int c = 0; c < 8; ++c) {
      int gj = j0 + tx * 8 + c;
      float val = acc[r][c] * alpha;
      if (diagv != nullptr && gi == gj) val += diagv[(size_t)b * N_VAR + gi] + SIGMA_C;
      Cb[(size_t)gi * J + gj] = val;
    }
  }
}

// ---------------------------------------------------------------------------
// K3: Gauss-Jordan inversion (SPD, diag-dominant; no pivoting).
// 512 threads/WG: thread t owns col c=t&255, rows rh*128+j (rh=t>>8, j<128).
// a[128] in VGPRs: 2 waves/SIMD -> 256-reg cap, ~150 used, NO scratch spill
// (the 1024-thread version capped at 128 regs and spilled -> 45 ms cold).
// ---------------------------------------------------------------------------
__global__ __launch_bounds__(512, 2) void k_invert(const float* __restrict__ Mk,
                                                   float* __restrict__ Mi) {
  int b = blockIdx.x;
  const float* src = Mk + (size_t)b * 65536;
  float* dst = Mi + (size_t)b * 65536;
  int t = threadIdx.x;
  int c = t & 255, rh = t >> 8;
  float a[128];
#pragma unroll
  for (int j = 0; j < 128; ++j) a[j] = src[(size_t)(rh * 128 + j) * 256 + c];

  __shared__ float colP[2][256];
  __shared__ float rowB[2][256];

  for (int k = 0; k < 256; ++k) {
    int cur = k & 1;
    int kh = k >> 7, kj = k & 127;
    if (c == k) {
      float4* cp4 = (float4*)&colP[cur][rh * 128];
#pragma unroll
      for (int jj = 0; jj < 32; ++jj)
        cp4[jj] = make_float4(a[4 * jj], a[4 * jj + 1], a[4 * jj + 2], a[4 * jj + 3]);
    }
    __syncthreads();
    float pivinv = 1.0f / colP[cur][k];
    if (rh == kh) {
      float v = (c == k) ? pivinv : a[kj] * pivinv;
      a[kj] = v;
      rowB[cur][c] = v;
    }
    __syncthreads();
    float rb = rowB[cur][c];
    float keep = a[kj];
    const float4* cp4 = (const float4*)&colP[cur][rh * 128];
#pragma unroll
    for (int jj = 0; jj < 32; ++jj) {
      float4 cv = cp4[jj];
      a[4 * jj + 0] -= rb * cv.x;
      a[4 * jj + 1] -= rb * cv.y;
      a[4 * jj + 2] -= rb * cv.z;
      a[4 * jj + 3] -= rb * cv.w;
    }
    if (rh == kh) a[kj] = keep;
    if (c == k) {
#pragma unroll
      for (int jj = 0; jj < 32; ++jj) {
        float4 cv = cp4[jj];
        a[4 * jj + 0] = -pivinv * cv.x;
        a[4 * jj + 1] = -pivinv * cv.y;
        a[4 * jj + 2] = -pivinv * cv.z;
        a[4 * jj + 3] = -pivinv * cv.w;
      }
      if (rh == kh) a[kj] = pivinv;
    }
  }
#pragma unroll
  for (int j = 0; j < 128; ++j) dst[(size_t)(rh * 128 + j) * 256 + c] = a[j];
}

// ---------------------------------------------------------------------------
// K4a: h = Minv * q  (column access via symmetry)
// ---------------------------------------------------------------------------
__global__ __launch_bounds__(256) void k_matvec_h(const float* __restrict__ Mi,
                                                  const float* __restrict__ q,
                                                  float* __restrict__ h) {
  int b = blockIdx.x, t = threadIdx.x;
  __shared__ float qs[256];
  qs[t] = q[(size_t)b * 256 + t];
  __syncthreads();
  const float* Mb = Mi + (size_t)b * 65536;
  float acc = 0.0f;
  for (int k = 0; k < 256; ++k) acc += Mb[(size_t)k * 256 + t] * qs[k];
  h[(size_t)b * 256 + t] = acc;
}

// K4b: d = A * h  via At columns
__global__ __launch_bounds__(512) void k_matvec_d(const float* __restrict__ At,
                                                  const float* __restrict__ h,
                                                  float* __restrict__ d) {
  int b = blockIdx.x, t = threadIdx.x;
  __shared__ float hs[256];
  if (t < 256) hs[t] = h[(size_t)b * 256 + t];
  __syncthreads();
  const float* Ab = At + (size_t)b * 131072;
  float acc = 0.0f;
  for (int n = 0; n < 256; ++n) acc += Ab[(size_t)n * 512 + t] * hs[n];
  d[(size_t)b * 512 + t] = acc;
}

// ---------------------------------------------------------------------------
// K5: zero the per-batch flags
// ---------------------------------------------------------------------------
__global__ __launch_bounds__(256) void k_zero(int* __restrict__ ctr, int n) {
  int i = blockIdx.x * 256 + threadIdx.x;
  if (i < n) ctr[i] = 0;
}

// ---------------------------------------------------------------------------
// K6: ADMM loop. 4 CUs per batch, register-resident G, relaxed-atomic sync.
// 256 WGs x 512 threads. blockIdx g: x=g&7 (XCD under round-robin dispatch),
// b=(g&7)+8*((g>>3)&7), s=g>>6 -> batch's 4 slices share an XCD (perf only).
// Slice s owns rows [s*128,s*128+128). Thread (wv=t>>6, l=t&63): rows
// {s*128+l, s*128+64+l} x cols [wv*64,wv*64+64) = 128 G-floats in VGPRs.
// 512 thr = 8 waves = 2/SIMD -> 256-reg cap; ~156 used -> exactly 1 WG/CU
// (2 WGs would need 624 regs/SIMD > 512) -> all 256 WGs co-resident ->
// spin-sync deadlock-free. Sync = relaxed agent atomics ONLY (no acquire ->
// no L2-invalidate storm; round-2 empirically validated relaxed visibility).
// ---------------------------------------------------------------------------
__global__ __launch_bounds__(512, 2) void k_admm4(
    const float* __restrict__ G, const float* __restrict__ dvec,
    const float* __restrict__ lv, const float* __restrict__ uv,
    float* __restrict__ wbuf, int* __restrict__ flags,
    float* __restrict__ Sbuf) {
  int g = blockIdx.x;
  int b = (g & 7) + 8 * ((g >> 3) & 7);
  int s = g >> 6;
  int t = threadIdx.x;
  int l = t & 63, wv = t >> 6;
  int c0 = wv * 64;

  __shared__ __align__(16) float wloc[512];
  __shared__ float part[8][128];

  // --- one-time: G strip into registers ---
  const float* Gb = G + (size_t)b * 262144;
  const float* g0p = Gb + (size_t)(s * 128 + l) * 512 + c0;
  const float* g1p = Gb + (size_t)(s * 128 + 64 + l) * 512 + c0;
  float G0[64], G1[64];
#pragma unroll
  for (int j = 0; j < 16; ++j) {
    float4 v0 = *(const float4*)(g0p + 4 * j);
    G0[4 * j + 0] = v0.x; G0[4 * j + 1] = v0.y;
    G0[4 * j + 2] = v0.z; G0[4 * j + 3] = v0.w;
    float4 v1 = *(const float4*)(g1p + 4 * j);
    G1[4 * j + 0] = v1.x; G1[4 * j + 1] = v1.y;
    G1[4 * j + 2] = v1.z; G1[4 * j + 3] = v1.w;
  }

  // --- per-row state (threads 0..127 own row s*128+t) ---
  float zreg = 0.0f, yreg = 0.0f, Sreg = 0.0f;
  float lreg = 0.0f, ureg = 0.0f, dreg = 0.0f;
  if (t < 128) {
    lreg = lv[(size_t)b * 512 + s * 128 + t];
    ureg = uv[(size_t)b * 512 + s * 128 + t];
    dreg = dvec[(size_t)b * 512 + s * 128 + t];
  }
  wloc[t] = 0.0f;  // w_0 = 0

  float* wb0 = wbuf + (size_t)b * 512;
  float* wb1 = wbuf + 32768 + (size_t)b * 512;
  int* flg = flags + b * 64;  // 4 flags, 64B-padded (stride 16 ints)
  const float4* wq4 = (const float4*)(wloc + c0);

  for (int it = 0; it < NITERS; ++it) {
    __syncthreads();  // Btop: wloc == w_it everywhere

    // partial zt: rows {l, 64+l} of slice, cols [c0, c0+64)
    float r0a = 0.f, r0b = 0.f, r1a = 0.f, r1b = 0.f;
#pragma unroll
    for (int j = 0; j < 8; ++j) {
      float4 wa = wq4[2 * j];       // uniform-address ds_read_b128 (broadcast)
      float4 wc = wq4[2 * j + 1];
      r0a += G0[8 * j + 0] * wa.x + G0[8 * j + 1] * wa.y +
             G0[8 * j + 2] * wa.z + G0[8 * j + 3] * wa.w;
      r1a += G1[8 * j + 0] * wa.x + G1[8 * j + 1] * wa.y +
             G1[8 * j + 2] * wa.z + G1[8 * j + 3] * wa.w;
      r0b += G0[8 * j + 4] * wc.x + G0[8 * j + 5] * wc.y +
             G0[8 * j + 6] * wc.z + G0[8 * j + 7] * wc.w;
      r1b += G1[8 * j + 4] * wc.x + G1[8 * j + 5] * wc.y +
             G1[8 * j + 6] * wc.z + G1[8 * j + 7] * wc.w;
    }
    part[wv][l] = r0a + r0b;
    part[wv][64 + l] = r1a + r1b;
    __syncthreads();  // B1: partials visible

    if (t < 128) {
      float w_old = RHO_C * zreg - yreg;  // == w_it[own row]
      Sreg = w_old - 0.6f * Sreg;         // S <- w + (1-alpha)*S
      float p = part[0][t] + part[1][t] + part[2][t] + part[3][t] +
                part[4][t] + part[5][t] + part[6][t] + part[7][t];
      float zt = p - dreg;
      float zh = ALPHA_C * zt + (1.0f - ALPHA_C) * zreg;
      float zc = zh + yreg * (1.0f / RHO_C);
      zc = fminf(fmaxf(zc, lreg), ureg);
      yreg += RHO_C * (zh - zc);
      zreg = zc;
      float wn = RHO_C * zreg - yreg;     // w_{it+1}[own row]
      wloc[s * 128 + t] = wn;
      if (it < NITERS - 1) {
        float* wp = ((it + 1) & 1) ? wb1 : wb0;
        __hip_atomic_store(&wp[s * 128 + t], wn, __ATOMIC_RELAXED,
                           __HIP_MEMORY_SCOPE_AGENT);
      }
    }

    if (it < NITERS - 1) {
      __syncthreads();  // B2: per-wave vmcnt(0) drain -> stores at coherence pt
      if (t == 0)
        __hip_atomic_store(&flg[s * 16], it + 1, __ATOMIC_RELEASE,
                           __HIP_MEMORY_SCOPE_AGENT);
      if (t < 4 && t != s) {
        while (__hip_atomic_load(&flg[t * 16], __ATOMIC_RELAXED,
                                 __HIP_MEMORY_SCOPE_AGENT) < it + 1)
          __builtin_amdgcn_s_sleep(1);
      }
      __syncthreads();  // B3: all 3 remote slices published
      if (t < 384) {
        int gr = (s * 128 + 128 + t) & 511;  // the 3 other slices' rows
        const float* wp = ((it + 1) & 1) ? wb1 : wb0;
        wloc[gr] = __hip_atomic_load(&wp[gr], __ATOMIC_RELAXED,
                                     __HIP_MEMORY_SCOPE_AGENT);
      }
      // loop-top barrier completes the exchange
    }
  }

  if (t < 128) Sbuf[(size_t)b * 512 + s * 128 + t] = Sreg;
}

// ---------------------------------------------------------------------------
// K7: epilogue  x = Minv * (alpha * A^T S - q)
// ---------------------------------------------------------------------------
__global__ __launch_bounds__(256) void k_final(
    const float* __restrict__ A, const float* __restrict__ q,
    const float* __restrict__ Mi, const float* __restrict__ Sbuf,
    float* __restrict__ xout) {
  int b = blockIdx.x, t = threadIdx.x;
  __shared__ float Ssh[512];
  __shared__ float uu[256];
  for (int i = t; i < 512; i += 256) Ssh[i] = Sbuf[(size_t)b * 512 + i];
  __syncthreads();
  const float* Ab = A + (size_t)b * 131072;
  float acc = 0.0f;
  for (int m = 0; m < 512; ++m) acc += Ab[(size_t)m * 256 + t] * Ssh[m];
  uu[t] = ALPHA_C * acc - q[(size_t)b * 256 + t];
  __syncthreads();
  const float* Mb = Mi + (size_t)b * 65536;
  float x = 0.0f;
  for (int kk = 0; kk < 256; ++kk) x += Mb[(size_t)kk * 256 + t] * uu[kk];
  xout[(size_t)b * 256 + t] = x;
}

// ---------------------------------------------------------------------------
extern "C" void kernel_launch(void* const* d_in, const int* in_sizes, int n_in,
                              void* d_out, int out_size, void* d_ws, size_t ws_size,
                              hipStream_t stream) {
  (void)in_sizes; (void)n_in; (void)out_size; (void)ws_size;
  const float* P = (const float*)d_in[0];
  const float* q = (const float*)d_in[1];
  const float* Av = (const float*)d_in[2];
  const float* lv = (const float*)d_in[3];
  const float* uv = (const float*)d_in[4];
  float* xout = (float*)d_out;

  float* ws = (float*)d_ws;
  float* At = ws;                       // 64*256*512; dies after k_matvec_d
  float* F  = ws;                       // alias of At
  float* Mi = ws + 8388608;             // 64*256*256
  float* Mk = ws + 12582912;            // dies after k_invert
  float* G  = ws + 12582912;            // 64*512*512 (over dead Mk)
  float* hv = ws + 29360128;            // 64*256
  float* dv = ws + 29376512;            // 64*512
  float* wbuf = ws + 29409280;          // 2*64*512 double-buffered w
  float* Sbuf = ws + 29474816;          // 64*512
  int*   flags = (int*)(ws + 29507584); // 64*64 ints (64B-padded flags)

  k_transpose<<<dim3(8, 16, 64), dim3(32, 8), 0, stream>>>(Av, At);
  k_ntgemm<<<dim3(4, 64), 256, 0, stream>>>(At, At, Mk, 256, 256, 512,
                                            131072LL, 131072LL, 65536LL,
                                            RHO_C, P, 2);
  k_invert<<<64, 512, 0, stream>>>(Mk, Mi);
  k_matvec_h<<<64, 256, 0, stream>>>(Mi, q, hv);
  k_matvec_d<<<64, 512, 0, stream>>>(At, hv, dv);
  k_ntgemm<<<dim3(8, 64), 256, 0, stream>>>(Av, Mi, F, 512, 256, 256,
                                            131072LL, 65536LL, 131072LL,
                                            1.0f, nullptr, 2);
  k_ntgemm<<<dim3(16, 64), 256, 0, stream>>>(F, Av, G, 512, 512, 256,
                                             131072LL, 131072LL, 262144LL,
                                             1.0f, nullptr, 4);
  k_zero<<<16, 256, 0, stream>>>(flags, 4096);
  k_admm4<<<256, 512, 0, stream>>>(G, dv, lv, uv, wbuf, flags, Sbuf);
  k_final<<<64, 256, 0, stream>>>(Av, q, Mi, Sbuf, xout);
}

// Round 5
// 3334.444 us; speedup vs baseline: 6.1542x; 2.0476x over previous
//
#include <hip/hip_runtime.h>
#include <hip/hip_fp16.h>

#define N_VAR 256
#define M_CON 512
#define BATCH 64
#define SIGMA_C 1e-6f
#define RHO_C 0.1f
#define ALPHA_C 1.6f
#define NITERS 500

// ---------------------------------------------------------------------------
// K1: transpose A [512][256] -> At [256][512] per batch
// ---------------------------------------------------------------------------
__global__ __launch_bounds__(256) void k_transpose(const float* __restrict__ A,
                                                   float* __restrict__ At) {
  __shared__ float tile[32][33];
  int b = blockIdx.z;
  int n0 = blockIdx.x * 32;
  int m0 = blockIdx.y * 32;
  const float* Ab = A + (size_t)b * (M_CON * N_VAR);
  float* Atb = At + (size_t)b * (M_CON * N_VAR);
  int tx = threadIdx.x, ty = threadIdx.y;  // (32, 8)
#pragma unroll
  for (int j = 0; j < 32; j += 8)
    tile[ty + j][tx] = Ab[(size_t)(m0 + ty + j) * N_VAR + n0 + tx];
  __syncthreads();
#pragma unroll
  for (int j = 0; j < 32; j += 8)
    Atb[(size_t)(n0 + ty + j) * M_CON + m0 + tx] = tile[tx][ty + j];
}

// ---------------------------------------------------------------------------
// K2: batched NT GEMM  C[i][j] = alpha * sum_k X[i][k]*Y[j][k]  (+ diag)
// ---------------------------------------------------------------------------
__global__ __launch_bounds__(256) void k_ntgemm(
    const float* __restrict__ X, const float* __restrict__ Y,
    float* __restrict__ C, int I, int J, int K,
    long long bsX, long long bsY, long long bsC, float alpha,
    const float* __restrict__ diagv, int tilesJ) {
  int b = blockIdx.y;
  int ti = blockIdx.x / tilesJ, tj = blockIdx.x % tilesJ;
  int i0 = ti * 128, j0 = tj * 128;
  const float* Xb = X + (size_t)b * bsX;
  const float* Yb = Y + (size_t)b * bsY;
  float* Cb = C + (size_t)b * bsC;
  __shared__ float Xs[16][128];
  __shared__ float Ys[16][128];
  int tid = threadIdx.x;
  int tx = tid & 15, ty = tid >> 4;
  float acc[8][8];
#pragma unroll
  for (int r = 0; r < 8; ++r)
#pragma unroll
    for (int c = 0; c < 8; ++c) acc[r][c] = 0.0f;

  for (int kk = 0; kk < K; kk += 16) {
#pragma unroll
    for (int v = 0; v < 2; ++v) {
      int idx = v * 256 + tid;
      int row = idx >> 2;
      int k4 = (idx & 3) * 4;
      float4 gx = *(const float4*)(Xb + (size_t)(i0 + row) * K + kk + k4);
      Xs[k4 + 0][row] = gx.x; Xs[k4 + 1][row] = gx.y;
      Xs[k4 + 2][row] = gx.z; Xs[k4 + 3][row] = gx.w;
      float4 gy = *(const float4*)(Yb + (size_t)(j0 + row) * K + kk + k4);
      Ys[k4 + 0][row] = gy.x; Ys[k4 + 1][row] = gy.y;
      Ys[k4 + 2][row] = gy.z; Ys[k4 + 3][row] = gy.w;
    }
    __syncthreads();
#pragma unroll
    for (int k = 0; k < 16; ++k) {
      float xr[8], yr[8];
      *(float4*)&xr[0] = *(float4*)&Xs[k][ty * 8];
      *(float4*)&xr[4] = *(float4*)&Xs[k][ty * 8 + 4];
      *(float4*)&yr[0] = *(float4*)&Ys[k][tx * 8];
      *(float4*)&yr[4] = *(float4*)&Ys[k][tx * 8 + 4];
#pragma unroll
      for (int r = 0; r < 8; ++r)
#pragma unroll
        for (int c = 0; c < 8; ++c) acc[r][c] += xr[r] * yr[c];
    }
    __syncthreads();
  }
#pragma unroll
  for (int r = 0; r < 8; ++r) {
    int gi = i0 + ty * 8 + r;
#pragma unroll
    for (int c = 0; c < 8; ++c) {
      int gj = j0 + tx * 8 + c;
      float val = acc[r][c] * alpha;
      if (diagv != nullptr && gi == gj) val += diagv[(size_t)b * N_VAR + gi] + SIGMA_C;
      Cb[(size_t)gi * J + gj] = val;
    }
  }
}

// ---------------------------------------------------------------------------
// K3: Gauss-Jordan inversion, NO dynamic register indexing (the a[kj] of the
// old version forced the whole array to scratch: 1.6 GB writes, 4.7 ms).
// 512 threads: thread t owns col c=t&255, row-half rh=t>>8 -> a[j]=B[rh*128+j][c]
// with j ALWAYS a literal (full unroll). The pivot-row element is stashed to
// LDS one step ahead (uniform scalar predicate rh==kh_next && j==kj_next),
// so step k reads its scaled pivot row from LDS, never a[runtime].
// In-place GJ step k: rowk *= pi; colk *= -pi (off-diag); diag=pi;
//                     B[i][j] -= oldcol[i]*oldrow[j]*pi elsewhere.
// ---------------------------------------------------------------------------
__global__ __launch_bounds__(512, 2) void k_invert(const float* __restrict__ Mk,
                                                   float* __restrict__ Mi) {
  int b = blockIdx.x;
  const float* src = Mk + (size_t)b * 65536;
  float* dst = Mi + (size_t)b * 65536;
  int t = threadIdx.x;
  int c = t & 255, rh = t >> 8;

  float a[128];
#pragma unroll
  for (int j = 0; j < 128; ++j) a[j] = src[(size_t)(rh * 128 + j) * 256 + c];

  __shared__ float colP[256];        // old pivot column (by global row)
  __shared__ float rowNext[2][256];  // unscaled next pivot row, double-buffered

  if (rh == 0) rowNext[0][c] = a[0];  // row 0 of original matrix

  for (int k = 0; k < 256; ++k) {
    int cur = k & 1, nxt = cur ^ 1;
    int kh = k >> 7, kj = k & 127;
    int khn = (k + 1) >> 7, kjn = (k + 1) & 127;
    bool last = (k == 255);

    if (c == k) {  // dump current column k (static indices only)
      float4* cp4 = (float4*)&colP[rh * 128];
#pragma unroll
      for (int jj = 0; jj < 32; ++jj)
        cp4[jj] = make_float4(a[4 * jj], a[4 * jj + 1], a[4 * jj + 2], a[4 * jj + 3]);
    }
    __syncthreads();  // B1: colP + rowNext[cur] visible

    float pivinv = 1.0f / colP[k];
    float rb = rowNext[cur][c] * pivinv;  // scaled pivot-row elem for col c
    if (c == k) rb = pivinv;              // diag of scaled pivot row
    bool pivcol = (c == k);
    bool myhalf = (rh == kh);
    bool stash = !last && (rh == khn);

    const float4* cp4 = (const float4*)&colP[rh * 128];
#pragma unroll
    for (int jj = 0; jj < 32; ++jj) {
      float4 cv = cp4[jj];
#pragma unroll
      for (int e = 0; e < 4; ++e) {
        int j = 4 * jj + e;
        float cp = (e == 0) ? cv.x : (e == 1) ? cv.y : (e == 2) ? cv.z : cv.w;
        float nv = a[j] - rb * cp;          // generic update
        float pv = -pivinv * cp;            // pivot-column value
        nv = pivcol ? pv : nv;              // per-lane cndmask
        if (myhalf && j == kj) nv = rb;     // uniform: pivot row (diag: rb=pivinv)
        a[j] = nv;
        if (stash && j == kjn)              // uniform scalar predicate
          rowNext[nxt][c] = nv;
      }
    }
    __syncthreads();  // B2: colP reads done before next dump; rowNext[nxt] done
  }

#pragma unroll
  for (int j = 0; j < 128; ++j) dst[(size_t)(rh * 128 + j) * 256 + c] = a[j];
}

// ---------------------------------------------------------------------------
// K4a: h = Minv * q  (column access via symmetry)
// ---------------------------------------------------------------------------
__global__ __launch_bounds__(256) void k_matvec_h(const float* __restrict__ Mi,
                                                  const float* __restrict__ q,
                                                  float* __restrict__ h) {
  int b = blockIdx.x, t = threadIdx.x;
  __shared__ float qs[256];
  qs[t] = q[(size_t)b * 256 + t];
  __syncthreads();
  const float* Mb = Mi + (size_t)b * 65536;
  float acc = 0.0f;
  for (int k = 0; k < 256; ++k) acc += Mb[(size_t)k * 256 + t] * qs[k];
  h[(size_t)b * 256 + t] = acc;
}

// K4b: d = A * h  via At columns
__global__ __launch_bounds__(512) void k_matvec_d(const float* __restrict__ At,
                                                  const float* __restrict__ h,
                                                  float* __restrict__ d) {
  int b = blockIdx.x, t = threadIdx.x;
  __shared__ float hs[256];
  if (t < 256) hs[t] = h[(size_t)b * 256 + t];
  __syncthreads();
  const float* Ab = At + (size_t)b * 131072;
  float acc = 0.0f;
  for (int n = 0; n < 256; ++n) acc += Ab[(size_t)n * 512 + t] * hs[n];
  d[(size_t)b * 512 + t] = acc;
}

// ---------------------------------------------------------------------------
// K5: zero the per-batch flags
// ---------------------------------------------------------------------------
__global__ __launch_bounds__(256) void k_zero(int* __restrict__ ctr, int n) {
  int i = blockIdx.x * 256 + threadIdx.x;
  if (i < n) ctr[i] = 0;
}

// ---------------------------------------------------------------------------
// K6: ADMM loop. 4 CUs per batch, register-resident G, relaxed-atomic sync.
// (unchanged from round 4 — dropped out of the top-5, sub-ms)
// ---------------------------------------------------------------------------
__global__ __launch_bounds__(512, 2) void k_admm4(
    const float* __restrict__ G, const float* __restrict__ dvec,
    const float* __restrict__ lv, const float* __restrict__ uv,
    float* __restrict__ wbuf, int* __restrict__ flags,
    float* __restrict__ Sbuf) {
  int g = blockIdx.x;
  int b = (g & 7) + 8 * ((g >> 3) & 7);
  int s = g >> 6;
  int t = threadIdx.x;
  int l = t & 63, wv = t >> 6;
  int c0 = wv * 64;

  __shared__ __align__(16) float wloc[512];
  __shared__ float part[8][128];

  const float* Gb = G + (size_t)b * 262144;
  const float* g0p = Gb + (size_t)(s * 128 + l) * 512 + c0;
  const float* g1p = Gb + (size_t)(s * 128 + 64 + l) * 512 + c0;
  float G0[64], G1[64];
#pragma unroll
  for (int j = 0; j < 16; ++j) {
    float4 v0 = *(const float4*)(g0p + 4 * j);
    G0[4 * j + 0] = v0.x; G0[4 * j + 1] = v0.y;
    G0[4 * j + 2] = v0.z; G0[4 * j + 3] = v0.w;
    float4 v1 = *(const float4*)(g1p + 4 * j);
    G1[4 * j + 0] = v1.x; G1[4 * j + 1] = v1.y;
    G1[4 * j + 2] = v1.z; G1[4 * j + 3] = v1.w;
  }

  float zreg = 0.0f, yreg = 0.0f, Sreg = 0.0f;
  float lreg = 0.0f, ureg = 0.0f, dreg = 0.0f;
  if (t < 128) {
    lreg = lv[(size_t)b * 512 + s * 128 + t];
    ureg = uv[(size_t)b * 512 + s * 128 + t];
    dreg = dvec[(size_t)b * 512 + s * 128 + t];
  }
  wloc[t] = 0.0f;  // w_0 = 0

  float* wb0 = wbuf + (size_t)b * 512;
  float* wb1 = wbuf + 32768 + (size_t)b * 512;
  int* flg = flags + b * 64;
  const float4* wq4 = (const float4*)(wloc + c0);

  for (int it = 0; it < NITERS; ++it) {
    __syncthreads();  // Btop: wloc == w_it everywhere

    float r0a = 0.f, r0b = 0.f, r1a = 0.f, r1b = 0.f;
#pragma unroll
    for (int j = 0; j < 8; ++j) {
      float4 wa = wq4[2 * j];
      float4 wc = wq4[2 * j + 1];
      r0a += G0[8 * j + 0] * wa.x + G0[8 * j + 1] * wa.y +
             G0[8 * j + 2] * wa.z + G0[8 * j + 3] * wa.w;
      r1a += G1[8 * j + 0] * wa.x + G1[8 * j + 1] * wa.y +
             G1[8 * j + 2] * wa.z + G1[8 * j + 3] * wa.w;
      r0b += G0[8 * j + 4] * wc.x + G0[8 * j + 5] * wc.y +
             G0[8 * j + 6] * wc.z + G0[8 * j + 7] * wc.w;
      r1b += G1[8 * j + 4] * wc.x + G1[8 * j + 5] * wc.y +
             G1[8 * j + 6] * wc.z + G1[8 * j + 7] * wc.w;
    }
    part[wv][l] = r0a + r0b;
    part[wv][64 + l] = r1a + r1b;
    __syncthreads();  // B1: partials visible

    if (t < 128) {
      float w_old = RHO_C * zreg - yreg;
      Sreg = w_old - 0.6f * Sreg;
      float p = part[0][t] + part[1][t] + part[2][t] + part[3][t] +
                part[4][t] + part[5][t] + part[6][t] + part[7][t];
      float zt = p - dreg;
      float zh = ALPHA_C * zt + (1.0f - ALPHA_C) * zreg;
      float zc = zh + yreg * (1.0f / RHO_C);
      zc = fminf(fmaxf(zc, lreg), ureg);
      yreg += RHO_C * (zh - zc);
      zreg = zc;
      float wn = RHO_C * zreg - yreg;
      wloc[s * 128 + t] = wn;
      if (it < NITERS - 1) {
        float* wp = ((it + 1) & 1) ? wb1 : wb0;
        __hip_atomic_store(&wp[s * 128 + t], wn, __ATOMIC_RELAXED,
                           __HIP_MEMORY_SCOPE_AGENT);
      }
    }

    if (it < NITERS - 1) {
      __syncthreads();  // B2: stores drained at coherence point
      if (t == 0)
        __hip_atomic_store(&flg[s * 16], it + 1, __ATOMIC_RELEASE,
                           __HIP_MEMORY_SCOPE_AGENT);
      if (t < 4 && t != s) {
        while (__hip_atomic_load(&flg[t * 16], __ATOMIC_RELAXED,
                                 __HIP_MEMORY_SCOPE_AGENT) < it + 1)
          __builtin_amdgcn_s_sleep(1);
      }
      __syncthreads();  // B3: all 3 remote slices published
      if (t < 384) {
        int gr = (s * 128 + 128 + t) & 511;
        const float* wp = ((it + 1) & 1) ? wb1 : wb0;
        wloc[gr] = __hip_atomic_load(&wp[gr], __ATOMIC_RELAXED,
                                     __HIP_MEMORY_SCOPE_AGENT);
      }
    }
  }

  if (t < 128) Sbuf[(size_t)b * 512 + s * 128 + t] = Sreg;
}

// ---------------------------------------------------------------------------
// K7: epilogue  x = Minv * (alpha * A^T S - q)
// ---------------------------------------------------------------------------
__global__ __launch_bounds__(256) void k_final(
    const float* __restrict__ A, const float* __restrict__ q,
    const float* __restrict__ Mi, const float* __restrict__ Sbuf,
    float* __restrict__ xout) {
  int b = blockIdx.x, t = threadIdx.x;
  __shared__ float Ssh[512];
  __shared__ float uu[256];
  for (int i = t; i < 512; i += 256) Ssh[i] = Sbuf[(size_t)b * 512 + i];
  __syncthreads();
  const float* Ab = A + (size_t)b * 131072;
  float acc = 0.0f;
  for (int m = 0; m < 512; ++m) acc += Ab[(size_t)m * 256 + t] * Ssh[m];
  uu[t] = ALPHA_C * acc - q[(size_t)b * 256 + t];
  __syncthreads();
  const float* Mb = Mi + (size_t)b * 65536;
  float x = 0.0f;
  for (int kk = 0; kk < 256; ++kk) x += Mb[(size_t)kk * 256 + t] * uu[kk];
  xout[(size_t)b * 256 + t] = x;
}

// ---------------------------------------------------------------------------
extern "C" void kernel_launch(void* const* d_in, const int* in_sizes, int n_in,
                              void* d_out, int out_size, void* d_ws, size_t ws_size,
                              hipStream_t stream) {
  (void)in_sizes; (void)n_in; (void)out_size; (void)ws_size;
  const float* P = (const float*)d_in[0];
  const float* q = (const float*)d_in[1];
  const float* Av = (const float*)d_in[2];
  const float* lv = (const float*)d_in[3];
  const float* uv = (const float*)d_in[4];
  float* xout = (float*)d_out;

  float* ws = (float*)d_ws;
  float* At = ws;                       // 64*256*512; dies after k_matvec_d
  float* F  = ws;                       // alias of At
  float* Mi = ws + 8388608;             // 64*256*256
  float* Mk = ws + 12582912;            // dies after k_invert
  float* G  = ws + 12582912;            // 64*512*512 (over dead Mk)
  float* hv = ws + 29360128;            // 64*256
  float* dv = ws + 29376512;            // 64*512
  float* wbuf = ws + 29409280;          // 2*64*512 double-buffered w
  float* Sbuf = ws + 29474816;          // 64*512
  int*   flags = (int*)(ws + 29507584); // 64*64 ints (64B-padded flags)

  k_transpose<<<dim3(8, 16, 64), dim3(32, 8), 0, stream>>>(Av, At);
  k_ntgemm<<<dim3(4, 64), 256, 0, stream>>>(At, At, Mk, 256, 256, 512,
                                            131072LL, 131072LL, 65536LL,
                                            RHO_C, P, 2);
  k_invert<<<64, 512, 0, stream>>>(Mk, Mi);
  k_matvec_h<<<64, 256, 0, stream>>>(Mi, q, hv);
  k_matvec_d<<<64, 512, 0, stream>>>(At, hv, dv);
  k_ntgemm<<<dim3(8, 64), 256, 0, stream>>>(Av, Mi, F, 512, 256, 256,
                                            131072LL, 65536LL, 131072LL,
                                            1.0f, nullptr, 2);
  k_ntgemm<<<dim3(16, 64), 256, 0, stream>>>(F, Av, G, 512, 512, 256,
                                             131072LL, 131072LL, 262144LL,
                                             1.0f, nullptr, 4);
  k_zero<<<16, 256, 0, stream>>>(flags, 4096);
  k_admm4<<<256, 512, 0, stream>>>(G, dv, lv, uv, wbuf, flags, Sbuf);
  k_final<<<64, 256, 0, stream>>>(Av, q, Mi, Sbuf, xout);
}

// Round 6
// 2499.467 us; speedup vs baseline: 8.2100x; 1.3341x over previous
//
#include <hip/hip_runtime.h>
#include <hip/hip_fp16.h>

#define N_VAR 256
#define M_CON 512
#define BATCH 64
#define SIGMA_C 1e-6f
#define RHO_C 0.1f
#define ALPHA_C 1.6f
#define NITERS 500

// ---------------------------------------------------------------------------
// K1: transpose A [512][256] -> At [256][512] per batch
// ---------------------------------------------------------------------------
__global__ __launch_bounds__(256) void k_transpose(const float* __restrict__ A,
                                                   float* __restrict__ At) {
  __shared__ float tile[32][33];
  int b = blockIdx.z;
  int n0 = blockIdx.x * 32;
  int m0 = blockIdx.y * 32;
  const float* Ab = A + (size_t)b * (M_CON * N_VAR);
  float* Atb = At + (size_t)b * (M_CON * N_VAR);
  int tx = threadIdx.x, ty = threadIdx.y;  // (32, 8)
#pragma unroll
  for (int j = 0; j < 32; j += 8)
    tile[ty + j][tx] = Ab[(size_t)(m0 + ty + j) * N_VAR + n0 + tx];
  __syncthreads();
#pragma unroll
  for (int j = 0; j < 32; j += 8)
    Atb[(size_t)(n0 + ty + j) * M_CON + m0 + tx] = tile[tx][ty + j];
}

// ---------------------------------------------------------------------------
// K2: batched NT GEMM  C[i][j] = alpha * sum_k X[i][k]*Y[j][k]  (+ diag)
// ---------------------------------------------------------------------------
__global__ __launch_bounds__(256) void k_ntgemm(
    const float* __restrict__ X, const float* __restrict__ Y,
    float* __restrict__ C, int I, int J, int K,
    long long bsX, long long bsY, long long bsC, float alpha,
    const float* __restrict__ diagv, int tilesJ) {
  int b = blockIdx.y;
  int ti = blockIdx.x / tilesJ, tj = blockIdx.x % tilesJ;
  int i0 = ti * 128, j0 = tj * 128;
  const float* Xb = X + (size_t)b * bsX;
  const float* Yb = Y + (size_t)b * bsY;
  float* Cb = C + (size_t)b * bsC;
  __shared__ float Xs[16][128];
  __shared__ float Ys[16][128];
  int tid = threadIdx.x;
  int tx = tid & 15, ty = tid >> 4;
  float acc[8][8];
#pragma unroll
  for (int r = 0; r < 8; ++r)
#pragma unroll
    for (int c = 0; c < 8; ++c) acc[r][c] = 0.0f;

  for (int kk = 0; kk < K; kk += 16) {
#pragma unroll
    for (int v = 0; v < 2; ++v) {
      int idx = v * 256 + tid;
      int row = idx >> 2;
      int k4 = (idx & 3) * 4;
      float4 gx = *(const float4*)(Xb + (size_t)(i0 + row) * K + kk + k4);
      Xs[k4 + 0][row] = gx.x; Xs[k4 + 1][row] = gx.y;
      Xs[k4 + 2][row] = gx.z; Xs[k4 + 3][row] = gx.w;
      float4 gy = *(const float4*)(Yb + (size_t)(j0 + row) * K + kk + k4);
      Ys[k4 + 0][row] = gy.x; Ys[k4 + 1][row] = gy.y;
      Ys[k4 + 2][row] = gy.z; Ys[k4 + 3][row] = gy.w;
    }
    __syncthreads();
#pragma unroll
    for (int k = 0; k < 16; ++k) {
      float xr[8], yr[8];
      *(float4*)&xr[0] = *(float4*)&Xs[k][ty * 8];
      *(float4*)&xr[4] = *(float4*)&Xs[k][ty * 8 + 4];
      *(float4*)&yr[0] = *(float4*)&Ys[k][tx * 8];
      *(float4*)&yr[4] = *(float4*)&Ys[k][tx * 8 + 4];
#pragma unroll
      for (int r = 0; r < 8; ++r)
#pragma unroll
        for (int c = 0; c < 8; ++c) acc[r][c] += xr[r] * yr[c];
    }
    __syncthreads();
  }
#pragma unroll
  for (int r = 0; r < 8; ++r) {
    int gi = i0 + ty * 8 + r;
#pragma unroll
    for (int c = 0; c < 8; ++c) {
      int gj = j0 + tx * 8 + c;
      float val = acc[r][c] * alpha;
      if (diagv != nullptr && gi == gj) val += diagv[(size_t)b * N_VAR + gi] + SIGMA_C;
      Cb[(size_t)gi * J + gj] = val;
    }
  }
}

// ---------------------------------------------------------------------------
// K3: Gauss-Jordan inversion, NO dynamic register indexing.
// (round-5 version: 4.7 ms -> out of top-5; unchanged)
// ---------------------------------------------------------------------------
__global__ __launch_bounds__(512, 2) void k_invert(const float* __restrict__ Mk,
                                                   float* __restrict__ Mi) {
  int b = blockIdx.x;
  const float* src = Mk + (size_t)b * 65536;
  float* dst = Mi + (size_t)b * 65536;
  int t = threadIdx.x;
  int c = t & 255, rh = t >> 8;

  float a[128];
#pragma unroll
  for (int j = 0; j < 128; ++j) a[j] = src[(size_t)(rh * 128 + j) * 256 + c];

  __shared__ float colP[256];
  __shared__ float rowNext[2][256];

  if (rh == 0) rowNext[0][c] = a[0];

  for (int k = 0; k < 256; ++k) {
    int cur = k & 1, nxt = cur ^ 1;
    int kh = k >> 7, kj = k & 127;
    int khn = (k + 1) >> 7, kjn = (k + 1) & 127;
    bool last = (k == 255);

    if (c == k) {
      float4* cp4 = (float4*)&colP[rh * 128];
#pragma unroll
      for (int jj = 0; jj < 32; ++jj)
        cp4[jj] = make_float4(a[4 * jj], a[4 * jj + 1], a[4 * jj + 2], a[4 * jj + 3]);
    }
    __syncthreads();

    float pivinv = 1.0f / colP[k];
    float rb = rowNext[cur][c] * pivinv;
    if (c == k) rb = pivinv;
    bool pivcol = (c == k);
    bool myhalf = (rh == kh);
    bool stash = !last && (rh == khn);

    const float4* cp4 = (const float4*)&colP[rh * 128];
#pragma unroll
    for (int jj = 0; jj < 32; ++jj) {
      float4 cv = cp4[jj];
#pragma unroll
      for (int e = 0; e < 4; ++e) {
        int j = 4 * jj + e;
        float cp = (e == 0) ? cv.x : (e == 1) ? cv.y : (e == 2) ? cv.z : cv.w;
        float nv = a[j] - rb * cp;
        float pv = -pivinv * cp;
        nv = pivcol ? pv : nv;
        if (myhalf && j == kj) nv = rb;
        a[j] = nv;
        if (stash && j == kjn)
          rowNext[nxt][c] = nv;
      }
    }
    __syncthreads();
  }

#pragma unroll
  for (int j = 0; j < 128; ++j) dst[(size_t)(rh * 128 + j) * 256 + c] = a[j];
}

// ---------------------------------------------------------------------------
// K4a: h = Minv * q  (column access via symmetry)
// ---------------------------------------------------------------------------
__global__ __launch_bounds__(256) void k_matvec_h(const float* __restrict__ Mi,
                                                  const float* __restrict__ q,
                                                  float* __restrict__ h) {
  int b = blockIdx.x, t = threadIdx.x;
  __shared__ float qs[256];
  qs[t] = q[(size_t)b * 256 + t];
  __syncthreads();
  const float* Mb = Mi + (size_t)b * 65536;
  float acc = 0.0f;
  for (int k = 0; k < 256; ++k) acc += Mb[(size_t)k * 256 + t] * qs[k];
  h[(size_t)b * 256 + t] = acc;
}

// K4b: d = A * h  via At columns
__global__ __launch_bounds__(512) void k_matvec_d(const float* __restrict__ At,
                                                  const float* __restrict__ h,
                                                  float* __restrict__ d) {
  int b = blockIdx.x, t = threadIdx.x;
  __shared__ float hs[256];
  if (t < 256) hs[t] = h[(size_t)b * 256 + t];
  __syncthreads();
  const float* Ab = At + (size_t)b * 131072;
  float acc = 0.0f;
  for (int n = 0; n < 256; ++n) acc += Ab[(size_t)n * 512 + t] * hs[n];
  d[(size_t)b * 512 + t] = acc;
}

// ---------------------------------------------------------------------------
// K6: ADMM loop. 4 CUs/batch, register-resident G, packed (tag|value) u64
// exchange: the published w value and its iteration tag travel in ONE relaxed
// agent-scope 8B atomic -> no release fence, no flag round trip, no B2/B3.
// Parity double-buffer (slot = (it+1)&1) makes tag skew safe: a WG can only
// publish it+3 (same parity as it+1) after every peer consumed it+1.
// ws is 0xAA-poisoned before every launch -> stale tags never match (<=500).
// Pollers (waves 2..7) overlap the z/y update (waves 0..1). 2 barriers/iter.
// ---------------------------------------------------------------------------
__global__ __launch_bounds__(512, 2) void k_admm4(
    const float* __restrict__ G, const float* __restrict__ dvec,
    const float* __restrict__ lv, const float* __restrict__ uv,
    unsigned long long* __restrict__ wtag, float* __restrict__ Sbuf) {
  int g = blockIdx.x;
  int b = (g & 7) + 8 * ((g >> 3) & 7);  // batch's 4 slices share an XCD (perf)
  int s = g >> 6;
  int t = threadIdx.x;
  int l = t & 63, wv = t >> 6;
  int c0 = wv * 64;

  __shared__ __align__(16) float wloc[512];
  __shared__ float part[8][128];

  // --- one-time: G strip into registers ---
  const float* Gb = G + (size_t)b * 262144;
  const float* g0p = Gb + (size_t)(s * 128 + l) * 512 + c0;
  const float* g1p = Gb + (size_t)(s * 128 + 64 + l) * 512 + c0;
  float G0[64], G1[64];
#pragma unroll
  for (int j = 0; j < 16; ++j) {
    float4 v0 = *(const float4*)(g0p + 4 * j);
    G0[4 * j + 0] = v0.x; G0[4 * j + 1] = v0.y;
    G0[4 * j + 2] = v0.z; G0[4 * j + 3] = v0.w;
    float4 v1 = *(const float4*)(g1p + 4 * j);
    G1[4 * j + 0] = v1.x; G1[4 * j + 1] = v1.y;
    G1[4 * j + 2] = v1.z; G1[4 * j + 3] = v1.w;
  }

  float zreg = 0.0f, yreg = 0.0f, Sreg = 0.0f;
  float lreg = 0.0f, ureg = 0.0f, dreg = 0.0f;
  if (t < 128) {
    lreg = lv[(size_t)b * 512 + s * 128 + t];
    ureg = uv[(size_t)b * 512 + s * 128 + t];
    dreg = dvec[(size_t)b * 512 + s * 128 + t];
  }
  wloc[t] = 0.0f;  // w_0 = 0

  unsigned long long* wt0 = wtag + (size_t)b * 512;
  unsigned long long* wt1 = wtag + 32768 + (size_t)b * 512;
  int gr = (s * 128 + t) & 511;  // poller target row (t>=128: other 3 slices)
  const float4* wq4 = (const float4*)(wloc + c0);

  for (int it = 0; it < NITERS; ++it) {
    __syncthreads();  // Btop: wloc == w_it everywhere

    // partial zt: rows {l, 64+l} of slice, cols [c0, c0+64)
    float r0a = 0.f, r0b = 0.f, r1a = 0.f, r1b = 0.f;
#pragma unroll
    for (int j = 0; j < 8; ++j) {
      float4 wa = wq4[2 * j];       // uniform-address ds_read_b128 (broadcast)
      float4 wc = wq4[2 * j + 1];
      r0a += G0[8 * j + 0] * wa.x + G0[8 * j + 1] * wa.y +
             G0[8 * j + 2] * wa.z + G0[8 * j + 3] * wa.w;
      r1a += G1[8 * j + 0] * wa.x + G1[8 * j + 1] * wa.y +
             G1[8 * j + 2] * wa.z + G1[8 * j + 3] * wa.w;
      r0b += G0[8 * j + 4] * wc.x + G0[8 * j + 5] * wc.y +
             G0[8 * j + 6] * wc.z + G0[8 * j + 7] * wc.w;
      r1b += G1[8 * j + 4] * wc.x + G1[8 * j + 5] * wc.y +
             G1[8 * j + 6] * wc.z + G1[8 * j + 7] * wc.w;
    }
    part[wv][l] = r0a + r0b;
    part[wv][64 + l] = r1a + r1b;
    __syncthreads();  // B1: partials visible; wloc reads of iter `it` done

    if (t < 128) {
      // update z,y,S for own row; publish packed w_{it+1}
      float w_old = RHO_C * zreg - yreg;
      Sreg = w_old - 0.6f * Sreg;         // S <- w + (1-alpha)*S
      float p = part[0][t] + part[1][t] + part[2][t] + part[3][t] +
                part[4][t] + part[5][t] + part[6][t] + part[7][t];
      float zt = p - dreg;
      float zh = ALPHA_C * zt + (1.0f - ALPHA_C) * zreg;
      float zc = zh + yreg * (1.0f / RHO_C);
      zc = fminf(fmaxf(zc, lreg), ureg);
      yreg += RHO_C * (zh - zc);
      zreg = zc;
      float wn = RHO_C * zreg - yreg;     // w_{it+1}[own row]
      wloc[s * 128 + t] = wn;
      if (it < NITERS - 1) {
        unsigned long long pk =
            ((unsigned long long)(unsigned)(it + 1) << 32) |
            (unsigned long long)__float_as_uint(wn);
        unsigned long long* wp = ((it + 1) & 1) ? wt1 : wt0;
        __hip_atomic_store(&wp[s * 128 + t], pk, __ATOMIC_RELAXED,
                           __HIP_MEMORY_SCOPE_AGENT);
      }
    } else if (it < NITERS - 1) {
      // poll own remote row's packed slot; payload rides in the atomic
      unsigned long long* wp = ((it + 1) & 1) ? wt1 : wt0;
      unsigned want = (unsigned)(it + 1);
      unsigned long long v;
      for (;;) {
        v = __hip_atomic_load(&wp[gr], __ATOMIC_RELAXED,
                              __HIP_MEMORY_SCOPE_AGENT);
        if ((unsigned)(v >> 32) == want) break;
        __builtin_amdgcn_s_sleep(1);
      }
      wloc[gr] = __uint_as_float((unsigned)(v & 0xffffffffu));
    }
    // loop-top barrier publishes wloc for iter it+1
  }

  if (t < 128) Sbuf[(size_t)b * 512 + s * 128 + t] = Sreg;
}

// ---------------------------------------------------------------------------
// K7: epilogue  x = Minv * (alpha * A^T S - q)
// ---------------------------------------------------------------------------
__global__ __launch_bounds__(256) void k_final(
    const float* __restrict__ A, const float* __restrict__ q,
    const float* __restrict__ Mi, const float* __restrict__ Sbuf,
    float* __restrict__ xout) {
  int b = blockIdx.x, t = threadIdx.x;
  __shared__ float Ssh[512];
  __shared__ float uu[256];
  for (int i = t; i < 512; i += 256) Ssh[i] = Sbuf[(size_t)b * 512 + i];
  __syncthreads();
  const float* Ab = A + (size_t)b * 131072;
  float acc = 0.0f;
  for (int m = 0; m < 512; ++m) acc += Ab[(size_t)m * 256 + t] * Ssh[m];
  uu[t] = ALPHA_C * acc - q[(size_t)b * 256 + t];
  __syncthreads();
  const float* Mb = Mi + (size_t)b * 65536;
  float x = 0.0f;
  for (int kk = 0; kk < 256; ++kk) x += Mb[(size_t)kk * 256 + t] * uu[kk];
  xout[(size_t)b * 256 + t] = x;
}

// ---------------------------------------------------------------------------
extern "C" void kernel_launch(void* const* d_in, const int* in_sizes, int n_in,
                              void* d_out, int out_size, void* d_ws, size_t ws_size,
                              hipStream_t stream) {
  (void)in_sizes; (void)n_in; (void)out_size; (void)ws_size;
  const float* P = (const float*)d_in[0];
  const float* q = (const float*)d_in[1];
  const float* Av = (const float*)d_in[2];
  const float* lv = (const float*)d_in[3];
  const float* uv = (const float*)d_in[4];
  float* xout = (float*)d_out;

  float* ws = (float*)d_ws;
  float* At = ws;                       // 64*256*512; dies after k_matvec_d
  float* F  = ws;                       // alias of At; dies after ntgemm G
  float* Mi = ws + 8388608;             // 64*256*256
  float* Mk = ws + 12582912;            // dies after k_invert
  float* G  = ws + 12582912;            // 64*512*512 (over dead Mk)
  float* hv = ws + 29360128;            // 64*256
  float* dv = ws + 29376512;            // 64*512
  float* Sbuf = ws + 29409280;          // 64*512
  // packed (tag|w) double buffer: 2*64*512 u64 = 512 KB, overlays dead At/F
  unsigned long long* wtag = (unsigned long long*)ws;

  k_transpose<<<dim3(8, 16, 64), dim3(32, 8), 0, stream>>>(Av, At);
  k_ntgemm<<<dim3(4, 64), 256, 0, stream>>>(At, At, Mk, 256, 256, 512,
                                            131072LL, 131072LL, 65536LL,
                                            RHO_C, P, 2);
  k_invert<<<64, 512, 0, stream>>>(Mk, Mi);
  k_matvec_h<<<64, 256, 0, stream>>>(Mi, q, hv);
  k_matvec_d<<<64, 512, 0, stream>>>(At, hv, dv);
  k_ntgemm<<<dim3(8, 64), 256, 0, stream>>>(Av, Mi, F, 512, 256, 256,
                                            131072LL, 65536LL, 131072LL,
                                            1.0f, nullptr, 2);
  k_ntgemm<<<dim3(16, 64), 256, 0, stream>>>(F, Av, G, 512, 512, 256,
                                             131072LL, 131072LL, 262144LL,
                                             1.0f, nullptr, 4);
  k_admm4<<<256, 512, 0, stream>>>(G, dv, lv, uv, wtag, Sbuf);
  k_final<<<64, 256, 0, stream>>>(Av, q, Mi, Sbuf, xout);
}

// Round 7
// 1629.416 us; speedup vs baseline: 12.5939x; 1.5340x over previous
//
#include <hip/hip_runtime.h>
#include <hip/hip_fp16.h>

#define N_VAR 256
#define M_CON 512
#define BATCH 64
#define SIGMA_C 1e-6f
#define RHO_C 0.1f
#define ALPHA_C 1.6f
#define NITERS 500

// ---------------------------------------------------------------------------
// K1: transpose A [512][256] -> At [256][512] per batch
// ---------------------------------------------------------------------------
__global__ __launch_bounds__(256) void k_transpose(const float* __restrict__ A,
                                                   float* __restrict__ At) {
  __shared__ float tile[32][33];
  int b = blockIdx.z;
  int n0 = blockIdx.x * 32;
  int m0 = blockIdx.y * 32;
  const float* Ab = A + (size_t)b * (M_CON * N_VAR);
  float* Atb = At + (size_t)b * (M_CON * N_VAR);
  int tx = threadIdx.x, ty = threadIdx.y;  // (32, 8)
#pragma unroll
  for (int j = 0; j < 32; j += 8)
    tile[ty + j][tx] = Ab[(size_t)(m0 + ty + j) * N_VAR + n0 + tx];
  __syncthreads();
#pragma unroll
  for (int j = 0; j < 32; j += 8)
    Atb[(size_t)(n0 + ty + j) * M_CON + m0 + tx] = tile[tx][ty + j];
}

// ---------------------------------------------------------------------------
// K2: batched NT GEMM  C[i][j] = alpha * sum_k X[i][k]*Y[j][k]  (+ diag)
// ---------------------------------------------------------------------------
__global__ __launch_bounds__(256) void k_ntgemm(
    const float* __restrict__ X, const float* __restrict__ Y,
    float* __restrict__ C, int I, int J, int K,
    long long bsX, long long bsY, long long bsC, float alpha,
    const float* __restrict__ diagv, int tilesJ) {
  int b = blockIdx.y;
  int ti = blockIdx.x / tilesJ, tj = blockIdx.x % tilesJ;
  int i0 = ti * 128, j0 = tj * 128;
  const float* Xb = X + (size_t)b * bsX;
  const float* Yb = Y + (size_t)b * bsY;
  float* Cb = C + (size_t)b * bsC;
  __shared__ float Xs[16][128];
  __shared__ float Ys[16][128];
  int tid = threadIdx.x;
  int tx = tid & 15, ty = tid >> 4;
  float acc[8][8];
#pragma unroll
  for (int r = 0; r < 8; ++r)
#pragma unroll
    for (int c = 0; c < 8; ++c) acc[r][c] = 0.0f;

  for (int kk = 0; kk < K; kk += 16) {
#pragma unroll
    for (int v = 0; v < 2; ++v) {
      int idx = v * 256 + tid;
      int row = idx >> 2;
      int k4 = (idx & 3) * 4;
      float4 gx = *(const float4*)(Xb + (size_t)(i0 + row) * K + kk + k4);
      Xs[k4 + 0][row] = gx.x; Xs[k4 + 1][row] = gx.y;
      Xs[k4 + 2][row] = gx.z; Xs[k4 + 3][row] = gx.w;
      float4 gy = *(const float4*)(Yb + (size_t)(j0 + row) * K + kk + k4);
      Ys[k4 + 0][row] = gy.x; Ys[k4 + 1][row] = gy.y;
      Ys[k4 + 2][row] = gy.z; Ys[k4 + 3][row] = gy.w;
    }
    __syncthreads();
#pragma unroll
    for (int k = 0; k < 16; ++k) {
      float xr[8], yr[8];
      *(float4*)&xr[0] = *(float4*)&Xs[k][ty * 8];
      *(float4*)&xr[4] = *(float4*)&Xs[k][ty * 8 + 4];
      *(float4*)&yr[0] = *(float4*)&Ys[k][tx * 8];
      *(float4*)&yr[4] = *(float4*)&Ys[k][tx * 8 + 4];
#pragma unroll
      for (int r = 0; r < 8; ++r)
#pragma unroll
        for (int c = 0; c < 8; ++c) acc[r][c] += xr[r] * yr[c];
    }
    __syncthreads();
  }
#pragma unroll
  for (int r = 0; r < 8; ++r) {
    int gi = i0 + ty * 8 + r;
#pragma unroll
    for (int c = 0; c < 8; ++c) {
      int gj = j0 + tx * 8 + c;
      float val = acc[r][c] * alpha;
      if (diagv != nullptr && gi == gj) val += diagv[(size_t)b * N_VAR + gi] + SIGMA_C;
      Cb[(size_t)gi * J + gj] = val;
    }
  }
}

// ---------------------------------------------------------------------------
// K3: BLOCKED Gauss-Jordan inversion, NB=8 (SPD, no pivoting; Schur
// complements of an SPD matrix stay SPD -> stable).
// Round-6 version was latency-bound: 256 steps x (dump->barrier->dependent
// LDS read->rcp->chain->barrier), VALUBusy 8.4%. Blocking amortizes the
// chain and barriers 8x: 32 steps, rank-8 update (8 FMA per element per
// step fed by 2 broadcast ds_read_b128). All register indices static;
// runtime indices touch LDS only. Uniform branches forced scalar via
// readfirstlane. 512 thr x a[128]: 2 waves/SIMD, ~170 regs < 256 cap.
// ---------------------------------------------------------------------------
__global__ __launch_bounds__(512, 2) void k_invert(const float* __restrict__ Mk,
                                                   float* __restrict__ Mi) {
  int b = blockIdx.x;
  const float* src = Mk + (size_t)b * 65536;
  float* dst = Mi + (size_t)b * 65536;
  int t = threadIdx.x;
  int c = t & 255, rh = t >> 8;

  float a[128];
#pragma unroll
  for (int j = 0; j < 128; ++j) a[j] = src[(size_t)(rh * 128 + j) * 256 + c];

  __shared__ float colPan[256][8];     // old pivot-column panel [row][f]
  __shared__ float rowPan[2][8][260];  // raw pivot-row panel [buf][e][c]
  __shared__ float PiSh[64];           // 8x8 pivot-block inverse (flat)
  __shared__ float Rp[8][260];         // scaled pivot-row panel R' [e][c]

  int rh_s = __builtin_amdgcn_readfirstlane(rh);        // wave-uniform
  int cw_s = __builtin_amdgcn_readfirstlane((t >> 6) & 3);  // c-quadrant of wave

  if (rh == 0) {
#pragma unroll
    for (int j = 0; j < 8; ++j) rowPan[0][j][c] = a[j];  // block 0 rows
  }
  __syncthreads();

  for (int s = 0; s < 32; ++s) {
    int kb = s * 8;
    int cur = s & 1, nxt = cur ^ 1;
    int kh = kb >> 7, kj = kb & 127;          // pivot rows: half kh, offset kj
    int khn = (kb + 8) >> 7, kjn = (kb + 8) & 127;
    bool mycol = (c >= kb) && (c < kb + 8);   // per-lane

    // Phase A: threads owning pivot columns dump OLD values (2 waves active)
    if (cw_s == (kb >> 6)) {
      if (mycol) {
        int f = c - kb;
#pragma unroll
        for (int j = 0; j < 128; ++j) colPan[rh * 128 + j][f] = a[j];
      }
    }
    // Phase B (overlapped): wave 0 inverts the 8x8 pivot block via shuffles
    if (t < 64) {
      int e = t >> 3, f = t & 7;
      float p = rowPan[cur][e][kb + f];
#pragma unroll
      for (int k2 = 0; k2 < 8; ++k2) {
        float piv = __shfl(p, k2 * 8 + k2);
        float rv = __shfl(p, k2 * 8 + f);
        float cv = __shfl(p, e * 8 + k2);
        float pivinv = 1.0f / piv;
        float srv = rv * pivinv;
        float gen = p - cv * srv;
        p = gen;
        if (e == k2) p = srv;
        if (f == k2) p = -cv * pivinv;
        if (e == k2 && f == k2) p = pivinv;
      }
      PiSh[t] = p;
    }
    __syncthreads();  // B_mid: colPan + PiSh ready (rowPan[cur] since B_top)

    // Phase C: rp[e] = R'[e][c] in registers; pivot cols carry Pi columns
    float rpan[8];
#pragma unroll
    for (int f2 = 0; f2 < 8; ++f2) rpan[f2] = rowPan[cur][f2][c];
    float rp[8];
#pragma unroll
    for (int e = 0; e < 8; ++e) {
      float4 p0 = *(const float4*)&PiSh[e * 8];      // broadcast
      float4 p1 = *(const float4*)&PiSh[e * 8 + 4];
      rp[e] = p0.x * rpan[0] + p0.y * rpan[1] + p0.z * rpan[2] + p0.w * rpan[3] +
              p1.x * rpan[4] + p1.y * rpan[5] + p1.z * rpan[6] + p1.w * rpan[7];
    }
    if (cw_s == (kb >> 6)) {
      if (mycol) {
        int f = c - kb;
#pragma unroll
        for (int e = 0; e < 8; ++e) rp[e] = PiSh[e * 8 + f];
      }
    }
#pragma unroll
    for (int e = 0; e < 8; ++e) Rp[e][c] = rp[e];  // both rh: same value, benign

    // Phase D: rank-8 update of all 128 owned elements
    bool myhalfk = (rh_s == kh);
    bool stashw = (s != 31) && (rh_s == khn);
#pragma unroll
    for (int j = 0; j < 128; ++j) {
      float4 c0 = *(const float4*)&colPan[rh * 128 + j][0];  // broadcast
      float4 c1 = *(const float4*)&colPan[rh * 128 + j][4];
      float aold = a[j];
      float nv = aold -
                 (c0.x * rp[0] + c0.y * rp[1] + c0.z * rp[2] + c0.w * rp[3] +
                  c1.x * rp[4] + c1.y * rp[5] + c1.z * rp[6] + c1.w * rp[7]);
      if (mycol) nv -= aold;                       // pivot-col correction
      if (myhalfk && j >= kj && j < kj + 8)        // uniform scalar branch
        nv = Rp[j - kj][c];                        // pivot-row override
      a[j] = nv;
      if (stashw && j >= kjn && j < kjn + 8)       // uniform scalar branch
        rowPan[nxt][j - kjn][c] = nv;              // stash next pivot rows
    }
    __syncthreads();  // B_top: stash/colPan/Rp consumption complete
  }

#pragma unroll
  for (int j = 0; j < 128; ++j) dst[(size_t)(rh * 128 + j) * 256 + c] = a[j];
}

// ---------------------------------------------------------------------------
// K4a: h = Minv * q  (column access via symmetry)
// ---------------------------------------------------------------------------
__global__ __launch_bounds__(256) void k_matvec_h(const float* __restrict__ Mi,
                                                  const float* __restrict__ q,
                                                  float* __restrict__ h) {
  int b = blockIdx.x, t = threadIdx.x;
  __shared__ float qs[256];
  qs[t] = q[(size_t)b * 256 + t];
  __syncthreads();
  const float* Mb = Mi + (size_t)b * 65536;
  float acc = 0.0f;
  for (int k = 0; k < 256; ++k) acc += Mb[(size_t)k * 256 + t] * qs[k];
  h[(size_t)b * 256 + t] = acc;
}

// K4b: d = A * h  via At columns
__global__ __launch_bounds__(512) void k_matvec_d(const float* __restrict__ At,
                                                  const float* __restrict__ h,
                                                  float* __restrict__ d) {
  int b = blockIdx.x, t = threadIdx.x;
  __shared__ float hs[256];
  if (t < 256) hs[t] = h[(size_t)b * 256 + t];
  __syncthreads();
  const float* Ab = At + (size_t)b * 131072;
  float acc = 0.0f;
  for (int n = 0; n < 256; ++n) acc += Ab[(size_t)n * 512 + t] * hs[n];
  d[(size_t)b * 512 + t] = acc;
}

// ---------------------------------------------------------------------------
// K6: ADMM loop. 4 CUs/batch, register-resident G, packed (tag|value) u64
// exchange (round-6: one relaxed agent-scope 8B atomic carries both data and
// iteration tag; parity double-buffer makes tag skew safe; 0xAA poison means
// stale tags never false-match). 2 barriers/iter.
// ---------------------------------------------------------------------------
__global__ __launch_bounds__(512, 2) void k_admm4(
    const float* __restrict__ G, const float* __restrict__ dvec,
    const float* __restrict__ lv, const float* __restrict__ uv,
    unsigned long long* __restrict__ wtag, float* __restrict__ Sbuf) {
  int g = blockIdx.x;
  int b = (g & 7) + 8 * ((g >> 3) & 7);
  int s = g >> 6;
  int t = threadIdx.x;
  int l = t & 63, wv = t >> 6;
  int c0 = wv * 64;

  __shared__ __align__(16) float wloc[512];
  __shared__ float part[8][128];

  const float* Gb = G + (size_t)b * 262144;
  const float* g0p = Gb + (size_t)(s * 128 + l) * 512 + c0;
  const float* g1p = Gb + (size_t)(s * 128 + 64 + l) * 512 + c0;
  float G0[64], G1[64];
#pragma unroll
  for (int j = 0; j < 16; ++j) {
    float4 v0 = *(const float4*)(g0p + 4 * j);
    G0[4 * j + 0] = v0.x; G0[4 * j + 1] = v0.y;
    G0[4 * j + 2] = v0.z; G0[4 * j + 3] = v0.w;
    float4 v1 = *(const float4*)(g1p + 4 * j);
    G1[4 * j + 0] = v1.x; G1[4 * j + 1] = v1.y;
    G1[4 * j + 2] = v1.z; G1[4 * j + 3] = v1.w;
  }

  float zreg = 0.0f, yreg = 0.0f, Sreg = 0.0f;
  float lreg = 0.0f, ureg = 0.0f, dreg = 0.0f;
  if (t < 128) {
    lreg = lv[(size_t)b * 512 + s * 128 + t];
    ureg = uv[(size_t)b * 512 + s * 128 + t];
    dreg = dvec[(size_t)b * 512 + s * 128 + t];
  }
  wloc[t] = 0.0f;  // w_0 = 0

  unsigned long long* wt0 = wtag + (size_t)b * 512;
  unsigned long long* wt1 = wtag + 32768 + (size_t)b * 512;
  int gr = (s * 128 + t) & 511;
  const float4* wq4 = (const float4*)(wloc + c0);

  for (int it = 0; it < NITERS; ++it) {
    __syncthreads();  // Btop: wloc == w_it everywhere

    float r0a = 0.f, r0b = 0.f, r1a = 0.f, r1b = 0.f;
#pragma unroll
    for (int j = 0; j < 8; ++j) {
      float4 wa = wq4[2 * j];
      float4 wc = wq4[2 * j + 1];
      r0a += G0[8 * j + 0] * wa.x + G0[8 * j + 1] * wa.y +
             G0[8 * j + 2] * wa.z + G0[8 * j + 3] * wa.w;
      r1a += G1[8 * j + 0] * wa.x + G1[8 * j + 1] * wa.y +
             G1[8 * j + 2] * wa.z + G1[8 * j + 3] * wa.w;
      r0b += G0[8 * j + 4] * wc.x + G0[8 * j + 5] * wc.y +
             G0[8 * j + 6] * wc.z + G0[8 * j + 7] * wc.w;
      r1b += G1[8 * j + 4] * wc.x + G1[8 * j + 5] * wc.y +
             G1[8 * j + 6] * wc.z + G1[8 * j + 7] * wc.w;
    }
    part[wv][l] = r0a + r0b;
    part[wv][64 + l] = r1a + r1b;
    __syncthreads();  // B1: partials visible; wloc reads of iter `it` done

    if (t < 128) {
      float w_old = RHO_C * zreg - yreg;
      Sreg = w_old - 0.6f * Sreg;
      float p = part[0][t] + part[1][t] + part[2][t] + part[3][t] +
                part[4][t] + part[5][t] + part[6][t] + part[7][t];
      float zt = p - dreg;
      float zh = ALPHA_C * zt + (1.0f - ALPHA_C) * zreg;
      float zc = zh + yreg * (1.0f / RHO_C);
      zc = fminf(fmaxf(zc, lreg), ureg);
      yreg += RHO_C * (zh - zc);
      zreg = zc;
      float wn = RHO_C * zreg - yreg;
      wloc[s * 128 + t] = wn;
      if (it < NITERS - 1) {
        unsigned long long pk =
            ((unsigned long long)(unsigned)(it + 1) << 32) |
            (unsigned long long)__float_as_uint(wn);
        unsigned long long* wp = ((it + 1) & 1) ? wt1 : wt0;
        __hip_atomic_store(&wp[s * 128 + t], pk, __ATOMIC_RELAXED,
                           __HIP_MEMORY_SCOPE_AGENT);
      }
    } else if (it < NITERS - 1) {
      unsigned long long* wp = ((it + 1) & 1) ? wt1 : wt0;
      unsigned want = (unsigned)(it + 1);
      unsigned long long v;
      for (;;) {
        v = __hip_atomic_load(&wp[gr], __ATOMIC_RELAXED,
                              __HIP_MEMORY_SCOPE_AGENT);
        if ((unsigned)(v >> 32) == want) break;
        __builtin_amdgcn_s_sleep(1);
      }
      wloc[gr] = __uint_as_float((unsigned)(v & 0xffffffffu));
    }
  }

  if (t < 128) Sbuf[(size_t)b * 512 + s * 128 + t] = Sreg;
}

// ---------------------------------------------------------------------------
// K7: epilogue  x = Minv * (alpha * A^T S - q)
// ---------------------------------------------------------------------------
__global__ __launch_bounds__(256) void k_final(
    const float* __restrict__ A, const float* __restrict__ q,
    const float* __restrict__ Mi, const float* __restrict__ Sbuf,
    float* __restrict__ xout) {
  int b = blockIdx.x, t = threadIdx.x;
  __shared__ float Ssh[512];
  __shared__ float uu[256];
  for (int i = t; i < 512; i += 256) Ssh[i] = Sbuf[(size_t)b * 512 + i];
  __syncthreads();
  const float* Ab = A + (size_t)b * 131072;
  float acc = 0.0f;
  for (int m = 0; m < 512; ++m) acc += Ab[(size_t)m * 256 + t] * Ssh[m];
  uu[t] = ALPHA_C * acc - q[(size_t)b * 256 + t];
  __syncthreads();
  const float* Mb = Mi + (size_t)b * 65536;
  float x = 0.0f;
  for (int kk = 0; kk < 256; ++kk) x += Mb[(size_t)kk * 256 + t] * uu[kk];
  xout[(size_t)b * 256 + t] = x;
}

// ---------------------------------------------------------------------------
extern "C" void kernel_launch(void* const* d_in, const int* in_sizes, int n_in,
                              void* d_out, int out_size, void* d_ws, size_t ws_size,
                              hipStream_t stream) {
  (void)in_sizes; (void)n_in; (void)out_size; (void)ws_size;
  const float* P = (const float*)d_in[0];
  const float* q = (const float*)d_in[1];
  const float* Av = (const float*)d_in[2];
  const float* lv = (const float*)d_in[3];
  const float* uv = (const float*)d_in[4];
  float* xout = (float*)d_out;

  float* ws = (float*)d_ws;
  float* At = ws;                       // 64*256*512; dies after k_matvec_d
  float* F  = ws;                       // alias of At; dies after ntgemm G
  float* Mi = ws + 8388608;             // 64*256*256
  float* Mk = ws + 12582912;            // dies after k_invert
  float* G  = ws + 12582912;            // 64*512*512 (over dead Mk)
  float* hv = ws + 29360128;            // 64*256
  float* dv = ws + 29376512;            // 64*512
  float* Sbuf = ws + 29409280;          // 64*512
  unsigned long long* wtag = (unsigned long long*)ws;  // overlays dead At/F

  k_transpose<<<dim3(8, 16, 64), dim3(32, 8), 0, stream>>>(Av, At);
  k_ntgemm<<<dim3(4, 64), 256, 0, stream>>>(At, At, Mk, 256, 256, 512,
                                            131072LL, 131072LL, 65536LL,
                                            RHO_C, P, 2);
  k_invert<<<64, 512, 0, stream>>>(Mk, Mi);
  k_matvec_h<<<64, 256, 0, stream>>>(Mi, q, hv);
  k_matvec_d<<<64, 512, 0, stream>>>(At, hv, dv);
  k_ntgemm<<<dim3(8, 64), 256, 0, stream>>>(Av, Mi, F, 512, 256, 256,
                                            131072LL, 65536LL, 131072LL,
                                            1.0f, nullptr, 2);
  k_ntgemm<<<dim3(16, 64), 256, 0, stream>>>(F, Av, G, 512, 512, 256,
                                             131072LL, 131072LL, 262144LL,
                                             1.0f, nullptr, 4);
  k_admm4<<<256, 512, 0, stream>>>(G, dv, lv, uv, wtag, Sbuf);
  k_final<<<64, 256, 0, stream>>>(Av, q, Mi, Sbuf, xout);
}